// Round 5
// baseline (157.468 us; speedup 1.0000x reference)
//
#include <hip/hip_runtime.h>
#include <math.h>

#define HW 512
#define NIMG 24              // 8*3 images per tensor
#define NB 362               // radial bins
#define PLANE (HW*HW)
#define NC 257               // spectral columns kept (0..256), Hermitian half
#define NG 65                // col-groups per image (4 cols each; cg64 ragged)
#define NPB (NIMG*NG)        // 1560 partial-bin blocks
#define CP2 133120           // floats per component per image: 65 cg * 512 * 4

// ws layout (float units) — R13/R15-proven:
#define OFF_PM  0                          // [NPB*NB] partial mag sums
#define OFF_PD  (NPB*NB)                   // [NPB*NB] partial d sums
#define OFF_PR  (2*NPB*NB)                 // P real, [img][cg][row][4]
#define OFF_PIm (OFF_PR + NIMG*CP2)        // P imag
#define OFF_TR  (OFF_PR + 2*NIMG*CP2)      // T real
#define OFF_TI  (OFF_PR + 3*NIMG*CP2)      // T imag
#define OFF_RM  (OFF_PR + 4*NIMG*CP2)      // [NIMG*NB] reduced mag sums
#define OFF_RD  (OFF_RM + NIMG*NB)         // [NIMG*NB] reduced d sums

// Padded staging index: A(p) = p + (p>>4). Kills the 16-way bank conflict on
// the binning float4 reads (start banks become 16-distinct); float4 pair reads
// stay contiguous because all pair starts have p mod 16 in {0,4,8,12}.
// Max A(511) = 542 < 544 (existing scratch size).
#define PIDX(p) ((p) + ((p) >> 4))

// Exact bin for ODD integer u,v (as floats): m2 = u^2+v^2 == 2 mod 8 is never
// a perfect even square, boundary gap >= 1/(4k) ~ 6.9e-4 >> 1ulp sqrt err.
__device__ __forceinline__ int rbin_odd(float u, float v) {
    return (int)(sqrtf(fmaf(u, u, v*v)) * 0.5f);
}

__device__ __forceinline__ void cmul(float& xr, float& xi, float wr, float wi) {
    float r = xr*wr - xi*wi;
    xi = xr*wi + xi*wr;
    xr = r;
}

// 8-point DFT in registers, natural order (validated R2-R17).
__device__ __forceinline__ void dft8(float ar[8], float ai[8]) {
    const float C = 0.70710678118654752440f;
    float t0r=ar[0]+ar[4], t0i=ai[0]+ai[4];
    float t1r=ar[0]-ar[4], t1i=ai[0]-ai[4];
    float t2r=ar[2]+ar[6], t2i=ai[2]+ai[6];
    float t3r=ar[2]-ar[6], t3i=ai[2]-ai[6];
    float E0r=t0r+t2r, E0i=t0i+t2i;
    float E2r=t0r-t2r, E2i=t0i-t2i;
    float E1r=t1r+t3i, E1i=t1i-t3r;
    float E3r=t1r-t3i, E3i=t1i+t3r;
    float u0r=ar[1]+ar[5], u0i=ai[1]+ai[5];
    float u1r=ar[1]-ar[5], u1i=ai[1]-ai[5];
    float u2r=ar[3]+ar[7], u2i=ai[3]+ai[7];
    float u3r=ar[3]-ar[7], u3i=ai[3]-ai[7];
    float O0r=u0r+u2r, O0i=u0i+u2i;
    float O2r=u0r-u2r, O2i=u0i-u2i;
    float O1r=u1r+u3i, O1i=u1i-u3r;
    float O3r=u1r-u3i, O3i=u1i+u3r;
    float W1r = C*(O1r+O1i), W1i = C*(O1i-O1r);
    float W2r = O2i,         W2i = -O2r;
    float W3r = C*(O3i-O3r), W3i = -C*(O3r+O3i);
    ar[0]=E0r+O0r; ai[0]=E0i+O0i;
    ar[4]=E0r-O0r; ai[4]=E0i-O0i;
    ar[1]=E1r+W1r; ai[1]=E1i+W1i;
    ar[5]=E1r-W1r; ai[5]=E1i-W1i;
    ar[2]=E2r+W2r; ai[2]=E2i+W2i;
    ar[6]=E2r-W2r; ai[6]=E2i-W2i;
    ar[3]=E3r+W3r; ai[3]=E3i+W3i;
    ar[7]=E3r-W3r; ai[7]=E3i-W3i;
}

__device__ __forceinline__ void twiddle7(float ar[8], float ai[8], float wr, float wi) {
    float pr = wr, pi = wi;
    cmul(ar[1], ai[1], pr, pi);
    #pragma unroll
    for (int k = 2; k < 8; ++k) {
        float nr = pr*wr - pi*wi;
        pi = pr*wi + pi*wr;
        pr = nr;
        cmul(ar[k], ai[k], pr, pi);
    }
}

// TWO interleaved 512-pt FFTs through one per-wave SCALAR scratch
// (R13-exact, proven for rowfft).
__device__ __forceinline__ void fft512x2(float Ar[8], float Ai[8],
                                         float Br[8], float Bi[8],
                                         float* Lr, float* Li, int lane) {
    float s1, c1, s2, c2;
    int k1 = lane >> 3, b = lane & 7;
    __sincosf((float)lane * (-6.28318530717958647692f/512.0f), &s1, &c1);
    __sincosf((float)b    * (-6.28318530717958647692f/64.0f),  &s2, &c2);
    dft8(Ar, Ai); twiddle7(Ar, Ai, c1, s1);
    dft8(Br, Bi); twiddle7(Br, Bi, c1, s1);
    #pragma unroll
    for (int j = 0; j < 8; ++j) { Lr[j*68+lane] = Ar[j]; Li[j*68+lane] = Ai[j]; }
    #pragma unroll
    for (int a = 0; a < 8; ++a) { Ar[a] = Lr[k1*68+8*a+b]; Ai[a] = Li[k1*68+8*a+b]; }
    #pragma unroll
    for (int j = 0; j < 8; ++j) { Lr[j*68+lane] = Br[j]; Li[j*68+lane] = Bi[j]; }
    dft8(Ar, Ai); twiddle7(Ar, Ai, c2, s2);
    #pragma unroll
    for (int a = 0; a < 8; ++a) { Br[a] = Lr[k1*68+8*a+b]; Bi[a] = Li[k1*68+8*a+b]; }
    dft8(Br, Bi); twiddle7(Br, Bi, c2, s2);
    #pragma unroll
    for (int cc = 0; cc < 8; ++cc) {
        int ad = k1*68 + 8*cc + ((b + cc) & 7);
        Lr[ad] = Ar[cc]; Li[ad] = Ai[cc];
    }
    #pragma unroll
    for (int bb = 0; bb < 8; ++bb) {
        int ad = k1*68 + 8*b + ((bb + b) & 7);
        Ar[bb] = Lr[ad]; Ai[bb] = Li[ad];
    }
    #pragma unroll
    for (int cc = 0; cc < 8; ++cc) {
        int ad = k1*68 + 8*cc + ((b + cc) & 7);
        Lr[ad] = Br[cc]; Li[ad] = Bi[cc];
    }
    dft8(Ar, Ai);
    #pragma unroll
    for (int bb = 0; bb < 8; ++bb) {
        int ad = k1*68 + 8*b + ((bb + b) & 7);
        Br[bb] = Lr[ad]; Bi[bb] = Li[ad];
    }
    dft8(Br, Bi);
}

// TWO interleaved 512-pt FFTs through one per-wave float2 scratch
// (R15-validated, proven best for colfft).
__device__ __forceinline__ void fft512x2f2(float Ar[8], float Ai[8],
                                           float Br[8], float Bi[8],
                                           float2* LC, int lane) {
    float s1, c1, s2, c2;
    int k1 = lane >> 3, b = lane & 7;
    __sincosf((float)lane * (-6.28318530717958647692f/512.0f), &s1, &c1);
    __sincosf((float)b    * (-6.28318530717958647692f/64.0f),  &s2, &c2);
    dft8(Ar, Ai); twiddle7(Ar, Ai, c1, s1);
    dft8(Br, Bi); twiddle7(Br, Bi, c1, s1);
    #pragma unroll
    for (int j = 0; j < 8; ++j) LC[j*68+lane] = make_float2(Ar[j], Ai[j]);
    #pragma unroll
    for (int a = 0; a < 8; ++a) {
        float2 v = LC[k1*68+8*a+b]; Ar[a] = v.x; Ai[a] = v.y;
    }
    #pragma unroll
    for (int j = 0; j < 8; ++j) LC[j*68+lane] = make_float2(Br[j], Bi[j]);
    dft8(Ar, Ai); twiddle7(Ar, Ai, c2, s2);
    #pragma unroll
    for (int a = 0; a < 8; ++a) {
        float2 v = LC[k1*68+8*a+b]; Br[a] = v.x; Bi[a] = v.y;
    }
    dft8(Br, Bi); twiddle7(Br, Bi, c2, s2);
    #pragma unroll
    for (int cc = 0; cc < 8; ++cc) {
        int ad = k1*68 + 8*cc + ((b + cc) & 7);
        LC[ad] = make_float2(Ar[cc], Ai[cc]);
    }
    #pragma unroll
    for (int bb = 0; bb < 8; ++bb) {
        int ad = k1*68 + 8*b + ((bb + b) & 7);
        float2 v = LC[ad]; Ar[bb] = v.x; Ai[bb] = v.y;
    }
    #pragma unroll
    for (int cc = 0; cc < 8; ++cc) {
        int ad = k1*68 + 8*cc + ((b + cc) & 7);
        LC[ad] = make_float2(Br[cc], Bi[cc]);
    }
    dft8(Ar, Ai);
    #pragma unroll
    for (int bb = 0; bb < 8; ++bb) {
        int ad = k1*68 + 8*b + ((bb + b) & 7);
        float2 v = LC[ad]; Br[bb] = v.x; Bi[bb] = v.y;
    }
    dft8(Br, Bi);
}

// Row stage (R13-exact, proven).
__global__ __launch_bounds__(256, 4) void k_rowfft(const float* __restrict__ pred,
                                                   const float* __restrict__ tgt,
                                                   float* __restrict__ ws) {
    __shared__ float smem[4352];
    int t = threadIdx.x, lane = t & 63, w = t >> 6;
    int b = blockIdx.x;
    int img = b >> 6;
    int r0 = (b & 63) << 3;
    int rA = r0 + 2*w;
    const float* pA = pred + (size_t)img*PLANE + (size_t)rA*HW;
    const float* tA = tgt  + (size_t)img*PLANE + (size_t)rA*HW;
    float arA[8], aiA[8], arB[8], aiB[8];
    #pragma unroll
    for (int j = 0; j < 8; ++j) {
        arA[j] = pA[64*j + lane];      aiA[j] = tA[64*j + lane];
        arB[j] = pA[HW + 64*j + lane]; aiB[j] = tA[HW + 64*j + lane];
    }
    float* Lr = smem + w*1088;
    float* Li = Lr + 544;
    fft512x2(arA, aiA, arB, aiB, Lr, Li, lane);
    float PrA[4], PiA[4], TrA[4], TiA[4], P256A=0.f, T256A=0.f;
    float PrB[4], PiB[4], TrB[4], TiB[4], P256B=0.f, T256B=0.f;
    #pragma unroll
    for (int d = 0; d < 8; ++d) {
        int k = (lane>>3) + ((lane&7)<<3) + (d<<6);
        Lr[k] = arA[d]; Li[k] = aiA[d];
    }
    #pragma unroll
    for (int m = 0; m < 4; ++m) {
        int kk = 64*m + lane, j2 = (512 - kk) & 511;
        float z1r = Lr[kk], z1i = Li[kk], z2r = Lr[j2], z2i = Li[j2];
        PrA[m] = 0.5f*(z1r+z2r); PiA[m] = 0.5f*(z1i-z2i);
        TrA[m] = 0.5f*(z1i+z2i); TiA[m] = 0.5f*(z2r-z1r);
    }
    if (lane == 0) { P256A = Lr[256]; T256A = Li[256]; }
    #pragma unroll
    for (int d = 0; d < 8; ++d) {
        int k = (lane>>3) + ((lane&7)<<3) + (d<<6);
        Lr[k] = arB[d]; Li[k] = aiB[d];
    }
    #pragma unroll
    for (int m = 0; m < 4; ++m) {
        int kk = 64*m + lane, j2 = (512 - kk) & 511;
        float z1r = Lr[kk], z1i = Li[kk], z2r = Lr[j2], z2i = Li[j2];
        PrB[m] = 0.5f*(z1r+z2r); PiB[m] = 0.5f*(z1i-z2i);
        TrB[m] = 0.5f*(z1i+z2i); TiB[m] = 0.5f*(z2r-z1r);
    }
    if (lane == 0) { P256B = Lr[256]; T256B = Li[256]; }

    float* tR = smem;                      // [8][260]
    float* tI = smem + 2080;
    __syncthreads();
    #pragma unroll
    for (int m = 0; m < 4; ++m) {
        int kk = 64*m + lane;
        tR[(2*w)*260 + kk]   = PrA[m]; tR[(2*w+1)*260 + kk] = PrB[m];
        tI[(2*w)*260 + kk]   = PiA[m]; tI[(2*w+1)*260 + kk] = PiB[m];
    }
    if (lane == 0) {
        tR[(2*w)*260 + 256] = P256A; tR[(2*w+1)*260 + 256] = P256B;
        tI[(2*w)*260 + 256] = 0.f;   tI[(2*w+1)*260 + 256] = 0.f;
    }
    __syncthreads();
    for (int idx = t; idx < 1040; idx += 256) {
        int comp = idx >= 520;
        int q = idx - (comp ? 520 : 0);
        int cg = q >> 3, rl = q & 7;
        const float* Tt = comp ? tI : tR;
        float4 v = *(const float4*)(Tt + rl*260 + 4*cg);
        float* outP = ws + (size_t)(comp ? OFF_PIm : OFF_PR)
                      + (size_t)img*CP2 + cg*2048 + (r0 + rl)*4;
        *(float4*)outP = v;
    }
    __syncthreads();
    #pragma unroll
    for (int m = 0; m < 4; ++m) {
        int kk = 64*m + lane;
        tR[(2*w)*260 + kk]   = TrA[m]; tR[(2*w+1)*260 + kk] = TrB[m];
        tI[(2*w)*260 + kk]   = TiA[m]; tI[(2*w+1)*260 + kk] = TiB[m];
    }
    if (lane == 0) {
        tR[(2*w)*260 + 256] = T256A; tR[(2*w+1)*260 + 256] = T256B;
        tI[(2*w)*260 + 256] = 0.f;   tI[(2*w+1)*260 + 256] = 0.f;
    }
    __syncthreads();
    for (int idx = t; idx < 1040; idx += 256) {
        int comp = idx >= 520;
        int q = idx - (comp ? 520 : 0);
        int cg = q >> 3, rl = q & 7;
        const float* Tt = comp ? tI : tR;
        float4 v = *(const float4*)(Tt + rl*260 + 4*cg);
        float* outP = ws + (size_t)(comp ? OFF_TI : OFF_TR)
                      + (size_t)img*CP2 + cg*2048 + (r0 + rl)*4;
        *(float4*)outP = v;
    }
}

// Flush helper: run-collapsed atomic pair.
__device__ __forceinline__ void flush2(float* binM, float* binD, int k,
                                       float aM, float aD) {
    atomicAdd(&binM[k], aM);
    atomicAdd(&binD[k], aD);
}

// Col stage R18: R15 structure, but the binning staging uses the padded
// PIDX layout -> conflict-free(er) float4 reads (was 16-way).
__global__ __launch_bounds__(256, 4) void k_colfft(const float* __restrict__ ws,
                                                   float* __restrict__ gPM,
                                                   float* __restrict__ gPD) {
    __shared__ __align__(16) float2 smem2[2176];
    __shared__ float binM[NB], binD[NB];
    int t = threadIdx.x, lane = t & 63, w = t >> 6;
    for (int j = t; j < NB; j += 256) { binM[j] = 0.f; binD[j] = 0.f; }
    __syncthreads();
    int b = blockIdx.x;
    int img = b / NG;
    int g = b - img*NG;
    int c = 4*g + w;
    if (c < NC) {
        float2* LC = smem2 + w*544;
        float prm[8], pim[8], trm[8], tim[8];
        size_t cbase = (size_t)img*CP2 + (size_t)(c >> 2)*2048 + (c & 3);
        const float* cPR = ws + OFF_PR  + cbase;
        const float* cPI = ws + OFF_PIm + cbase;
        const float* cTR = ws + OFF_TR  + cbase;
        const float* cTI = ws + OFF_TI  + cbase;
        #pragma unroll
        for (int j = 0; j < 8; ++j) {
            int o = (64*j + lane) << 2;
            prm[j] = cPR[o]; pim[j] = cPI[o];
            trm[j] = cTR[o]; tim[j] = cTI[o];
        }
        fft512x2f2(prm, pim, trm, tim, LC, lane);
        #pragma unroll
        for (int d = 0; d < 8; ++d) {
            int ky = (lane>>3) + ((lane&7)<<3) + (d<<6);
            float sp  = prm[d]*prm[d] + pim[d]*pim[d];
            float st_ = trm[d]*trm[d] + tim[d]*tim[d];
            float diff = sp - st_;
            float er = prm[d] + 1e-8f;
            LC[PIDX(ky)] = make_float2(10.0f * __logf(er*er + pim[d]*pim[d]), diff*diff);
        }
        __builtin_amdgcn_wave_barrier();
        // ---- contiguous-pair binning on the padded layout ----
        int p0 = 4*lane;
        float4 q0  = *(const float4*)(LC + PIDX(p0));        // elems p0, p0+1
        float4 q1  = *(const float4*)(LC + PIDX(p0) + 2);    // elems p0+2, p0+3
        float4 r0v = *(const float4*)(LC + PIDX(508 - p0));  // elems 508-p0, 509-p0
        float4 r1v = *(const float4*)(LC + PIDX(508 - p0) + 2); // 510-p0, 511-p0
        float2 e2 = LC[PIDX(p0 + 4)];                        // elem p0+4 (<=256)
        float2 g2 = LC[PIDX((512 - p0) & 511)];
        // main pass: s[j] = L[p0+j] + L[511-(p0+j)]
        float sM[4], sD[4];
        sM[0]=q0.x+r1v.z; sM[1]=q0.z+r1v.x; sM[2]=q1.x+r0v.z; sM[3]=q1.z+r0v.x;
        sD[0]=q0.y+r1v.w; sD[1]=q0.w+r1v.y; sD[2]=q1.y+r0v.w; sD[3]=q1.w+r0v.y;
        float v1 = (c == 256) ? 511.0f : (float)(2*c + 1);
        {
            int kp = rbin_odd((float)(2*p0 + 1), v1);
            float aM = sM[0], aD = sD[0];
            #pragma unroll
            for (int j = 1; j < 4; ++j) {
                int k = rbin_odd((float)(2*(p0 + j) + 1), v1);
                if (k == kp) { aM += sM[j]; aD += sD[j]; }
                else { flush2(binM, binD, kp, aM, aD); kp = k; aM = sM[j]; aD = sD[j]; }
            }
            flush2(binM, binD, kp, aM, aD);
        }
        if (c >= 1 && c <= 255) {
            // mirror pass: s2[j] = L[(512-(p0+j))&511] + L[p0+j+1]
            float s2M[4], s2D[4];
            s2M[0]=g2.x+q0.z;   s2D[0]=g2.y+q0.w;
            s2M[1]=r1v.z+q1.x;  s2D[1]=r1v.w+q1.y;
            s2M[2]=r1v.x+q1.z;  s2D[2]=r1v.y+q1.w;
            s2M[3]=r0v.z+e2.x;  s2D[3]=r0v.w+e2.y;
            float v2 = (float)(2*c - 1);
            int kp = rbin_odd((float)(2*p0 + 1), v2);
            float aM = s2M[0], aD = s2D[0];
            #pragma unroll
            for (int j = 1; j < 4; ++j) {
                int k = rbin_odd((float)(2*(p0 + j) + 1), v2);
                if (k == kp) { aM += s2M[j]; aD += s2D[j]; }
                else { flush2(binM, binD, kp, aM, aD); kp = k; aM = s2M[j]; aD = s2D[j]; }
            }
            flush2(binM, binD, kp, aM, aD);
        }
    }
    __syncthreads();
    for (int j = t; j < NB; j += 256) {
        gPM[(size_t)b*NB + j] = binM[j];
        gPD[(size_t)b*NB + j] = binD[j];
    }
}

// Partial-bin reduction (R13-proven, NG=65).
__global__ __launch_bounds__(256) void k_reduce(const float* __restrict__ gPM,
                                                const float* __restrict__ gPD,
                                                float* __restrict__ rM,
                                                float* __restrict__ rD) {
    __shared__ float sm[8][33], sd2[8][33];
    int b = blockIdx.x;
    int img = b / 12, ch = b - img*12;
    int jl = threadIdx.x & 31, gs = threadIdx.x >> 5;
    int j = ch*32 + jl;
    float aM = 0.f, aD = 0.f;
    if (j < NB) {
        for (int g = gs; g < NG; g += 8) {
            aM += gPM[(size_t)(img*NG + g)*NB + j];
            aD += gPD[(size_t)(img*NG + g)*NB + j];
        }
    }
    sm[gs][jl] = aM; sd2[gs][jl] = aD;
    __syncthreads();
    if (threadIdx.x < 32 && j < NB) {
        float tM = 0.f, tD = 0.f;
        #pragma unroll
        for (int s = 0; s < 8; ++s) { tM += sm[s][jl]; tD += sd2[s][jl]; }
        rM[img*NB + j] = tM;
        rD[img*NB + j] = tD;
    }
}

// Per-image final (R13-proven, unchanged).
__global__ __launch_bounds__(512) void k_final(const float* __restrict__ rM,
                                               const float* __restrict__ rD,
                                               float* __restrict__ out) {
    __shared__ int cnt[NB];
    __shared__ float meanb[NB];
    __shared__ float dsum[NB];
    __shared__ float rmin[512], rmax[512];
    __shared__ double sred[512];
    int t = threadIdx.x, img = blockIdx.x;
    for (int j = t; j < NB; j += 512) cnt[j] = 0;
    __syncthreads();
    {   // thread handles 128 contiguous v for fixed u: q = t*128 + i
        float u = (float)(2*(t >> 1) + 1);
        int vb = (t & 1) << 7;
        int kp = rbin_odd(u, (float)(2*vb + 1));
        int acc = 4;
        for (int i = 1; i < 128; ++i) {
            int k = rbin_odd(u, (float)(2*(vb + i) + 1));
            if (k == kp) acc += 4;
            else { atomicAdd(&cnt[kp], acc); kp = k; acc = 4; }
        }
        atomicAdd(&cnt[kp], acc);
    }
    __syncthreads();
    for (int j = t; j < NB; j += 512) {
        meanb[j] = rM[img*NB + j] / (float)cnt[j];
        dsum[j]  = rD[img*NB + j];
    }
    __syncthreads();
    float vmin = INFINITY, vmax = -INFINITY;
    if (t >= 1 && t <= 360) { vmin = meanb[t]; vmax = meanb[t]; }
    rmin[t] = vmin; rmax[t] = vmax;
    __syncthreads();
    for (int s = 256; s > 0; s >>= 1) {
        if (t < s) {
            float a = rmin[t], bb = rmin[t+s];
            rmin[t] = (a != a || bb != bb) ? __int_as_float(0x7fc00000) : fminf(a, bb);
            a = rmax[t]; bb = rmax[t+s];
            rmax[t] = (a != a || bb != bb) ? __int_as_float(0x7fc00000) : fmaxf(a, bb);
        }
        __syncthreads();
    }
    float pmin = rmin[0], pmax = rmax[0];
    double part = 0.0;
    for (int k = t; k < NB; k += 512) {
        float wgt;
        if (k == NB - 1) {
            wgt = 1.0f;
        } else {
            int idx = (k == 0) ? 1 : k;
            float e = (meanb[idx] - pmin) / (pmax - pmin);
            float wv = 1.0f - e;
            if (wv != wv) wv = 0.0f;
            wv = fminf(fmaxf(wv, 0.0f), 1.0f);
            wgt = wv;
        }
        part += (double)wgt * (double)dsum[k];
    }
    sred[t] = part;
    __syncthreads();
    for (int s = 256; s > 0; s >>= 1) {
        if (t < s) sred[t] += sred[t+s];
        __syncthreads();
    }
    if (t == 0) atomicAdd(out, (float)(sred[0] / 6291456.0));
}

extern "C" void kernel_launch(void* const* d_in, const int* in_sizes, int n_in,
                              void* d_out, int out_size, void* d_ws, size_t ws_size,
                              hipStream_t stream) {
    const float* pred = (const float*)d_in[0];
    const float* tgt  = (const float*)d_in[1];
    float* ws = (float*)d_ws;
    hipMemsetAsync(d_out, 0, sizeof(float), stream);
    k_rowfft<<<NIMG*64, 256, 0, stream>>>(pred, tgt, ws);
    k_colfft<<<NPB, 256, 0, stream>>>(ws, ws + OFF_PM, ws + OFF_PD);
    k_reduce<<<NIMG*12, 256, 0, stream>>>(ws + OFF_PM, ws + OFF_PD,
                                          ws + OFF_RM, ws + OFF_RD);
    k_final<<<NIMG, 512, 0, stream>>>(ws + OFF_RM, ws + OFF_RD, (float*)d_out);
}

// Round 6
// 153.484 us; speedup vs baseline: 1.0260x; 1.0260x over previous
//
#include <hip/hip_runtime.h>
#include <math.h>

#define HW 512
#define NIMG 24              // 8*3 images per tensor
#define NB 362               // radial bins
#define PLANE (HW*HW)
#define NC 257               // spectral columns kept (0..256), Hermitian half
#define NG 65                // col-groups per image (4 cols each; cg64 ragged)
#define NPB (NIMG*NG)        // 1560 partial-bin blocks
#define CP2 133120           // floats per component per image: 65 cg * 512 * 4

// ws layout (float units) — R13/R15-proven:
#define OFF_PM  0                          // [NPB*NB] partial mag sums
#define OFF_PD  (NPB*NB)                   // [NPB*NB] partial d sums
#define OFF_PR  (2*NPB*NB)                 // P real, [img][cg][row][4]
#define OFF_PIm (OFF_PR + NIMG*CP2)        // P imag
#define OFF_TR  (OFF_PR + 2*NIMG*CP2)      // T real
#define OFF_TI  (OFF_PR + 3*NIMG*CP2)      // T imag
#define OFF_RM  (OFF_PR + 4*NIMG*CP2)      // [NIMG*NB] reduced mag sums
#define OFF_RD  (OFF_RM + NIMG*NB)         // [NIMG*NB] reduced d sums

// Exact bin for ODD integer u,v (as floats): m2 = u^2+v^2 == 2 mod 8 is never
// a perfect even square, boundary gap >= 1/(4k) ~ 6.9e-4 >> 1ulp sqrt err.
__device__ __forceinline__ int rbin_odd(float u, float v) {
    return (int)(sqrtf(fmaf(u, u, v*v)) * 0.5f);
}

__device__ __forceinline__ void cmul(float& xr, float& xi, float wr, float wi) {
    float r = xr*wr - xi*wi;
    xi = xr*wi + xi*wr;
    xr = r;
}

// 8-point DFT in registers, natural order (validated R2-R18).
__device__ __forceinline__ void dft8(float ar[8], float ai[8]) {
    const float C = 0.70710678118654752440f;
    float t0r=ar[0]+ar[4], t0i=ai[0]+ai[4];
    float t1r=ar[0]-ar[4], t1i=ai[0]-ai[4];
    float t2r=ar[2]+ar[6], t2i=ai[2]+ai[6];
    float t3r=ar[2]-ar[6], t3i=ai[2]-ai[6];
    float E0r=t0r+t2r, E0i=t0i+t2i;
    float E2r=t0r-t2r, E2i=t0i-t2i;
    float E1r=t1r+t3i, E1i=t1i-t3r;
    float E3r=t1r-t3i, E3i=t1i+t3r;
    float u0r=ar[1]+ar[5], u0i=ai[1]+ai[5];
    float u1r=ar[1]-ar[5], u1i=ai[1]-ai[5];
    float u2r=ar[3]+ar[7], u2i=ai[3]+ai[7];
    float u3r=ar[3]-ar[7], u3i=ai[3]-ai[7];
    float O0r=u0r+u2r, O0i=u0i+u2i;
    float O2r=u0r-u2r, O2i=u0i-u2i;
    float O1r=u1r+u3i, O1i=u1i-u3r;
    float O3r=u1r-u3i, O3i=u1i+u3r;
    float W1r = C*(O1r+O1i), W1i = C*(O1i-O1r);
    float W2r = O2i,         W2i = -O2r;
    float W3r = C*(O3i-O3r), W3i = -C*(O3r+O3i);
    ar[0]=E0r+O0r; ai[0]=E0i+O0i;
    ar[4]=E0r-O0r; ai[4]=E0i-O0i;
    ar[1]=E1r+W1r; ai[1]=E1i+W1i;
    ar[5]=E1r-W1r; ai[5]=E1i-W1i;
    ar[2]=E2r+W2r; ai[2]=E2i+W2i;
    ar[6]=E2r-W2r; ai[6]=E2i-W2i;
    ar[3]=E3r+W3r; ai[3]=E3i+W3i;
    ar[7]=E3r-W3r; ai[7]=E3i-W3i;
}

__device__ __forceinline__ void twiddle7(float ar[8], float ai[8], float wr, float wi) {
    float pr = wr, pi = wi;
    cmul(ar[1], ai[1], pr, pi);
    #pragma unroll
    for (int k = 2; k < 8; ++k) {
        float nr = pr*wr - pi*wi;
        pi = pr*wi + pi*wr;
        pr = nr;
        cmul(ar[k], ai[k], pr, pi);
    }
}

// TWO interleaved 512-pt FFTs through one per-wave SCALAR scratch
// (R13-exact, proven for rowfft).
__device__ __forceinline__ void fft512x2(float Ar[8], float Ai[8],
                                         float Br[8], float Bi[8],
                                         float* Lr, float* Li, int lane) {
    float s1, c1, s2, c2;
    int k1 = lane >> 3, b = lane & 7;
    __sincosf((float)lane * (-6.28318530717958647692f/512.0f), &s1, &c1);
    __sincosf((float)b    * (-6.28318530717958647692f/64.0f),  &s2, &c2);
    dft8(Ar, Ai); twiddle7(Ar, Ai, c1, s1);
    dft8(Br, Bi); twiddle7(Br, Bi, c1, s1);
    #pragma unroll
    for (int j = 0; j < 8; ++j) { Lr[j*68+lane] = Ar[j]; Li[j*68+lane] = Ai[j]; }
    #pragma unroll
    for (int a = 0; a < 8; ++a) { Ar[a] = Lr[k1*68+8*a+b]; Ai[a] = Li[k1*68+8*a+b]; }
    #pragma unroll
    for (int j = 0; j < 8; ++j) { Lr[j*68+lane] = Br[j]; Li[j*68+lane] = Bi[j]; }
    dft8(Ar, Ai); twiddle7(Ar, Ai, c2, s2);
    #pragma unroll
    for (int a = 0; a < 8; ++a) { Br[a] = Lr[k1*68+8*a+b]; Bi[a] = Li[k1*68+8*a+b]; }
    dft8(Br, Bi); twiddle7(Br, Bi, c2, s2);
    #pragma unroll
    for (int cc = 0; cc < 8; ++cc) {
        int ad = k1*68 + 8*cc + ((b + cc) & 7);
        Lr[ad] = Ar[cc]; Li[ad] = Ai[cc];
    }
    #pragma unroll
    for (int bb = 0; bb < 8; ++bb) {
        int ad = k1*68 + 8*b + ((bb + b) & 7);
        Ar[bb] = Lr[ad]; Ai[bb] = Li[ad];
    }
    #pragma unroll
    for (int cc = 0; cc < 8; ++cc) {
        int ad = k1*68 + 8*cc + ((b + cc) & 7);
        Lr[ad] = Br[cc]; Li[ad] = Bi[cc];
    }
    dft8(Ar, Ai);
    #pragma unroll
    for (int bb = 0; bb < 8; ++bb) {
        int ad = k1*68 + 8*b + ((bb + b) & 7);
        Br[bb] = Lr[ad]; Bi[bb] = Li[ad];
    }
    dft8(Br, Bi);
}

// TWO interleaved 512-pt FFTs through one per-wave float2 scratch
// (R15-exact, proven best for colfft: 41.7 us).
__device__ __forceinline__ void fft512x2f2(float Ar[8], float Ai[8],
                                           float Br[8], float Bi[8],
                                           float2* LC, int lane) {
    float s1, c1, s2, c2;
    int k1 = lane >> 3, b = lane & 7;
    __sincosf((float)lane * (-6.28318530717958647692f/512.0f), &s1, &c1);
    __sincosf((float)b    * (-6.28318530717958647692f/64.0f),  &s2, &c2);
    dft8(Ar, Ai); twiddle7(Ar, Ai, c1, s1);
    dft8(Br, Bi); twiddle7(Br, Bi, c1, s1);
    #pragma unroll
    for (int j = 0; j < 8; ++j) LC[j*68+lane] = make_float2(Ar[j], Ai[j]);
    #pragma unroll
    for (int a = 0; a < 8; ++a) {
        float2 v = LC[k1*68+8*a+b]; Ar[a] = v.x; Ai[a] = v.y;
    }
    #pragma unroll
    for (int j = 0; j < 8; ++j) LC[j*68+lane] = make_float2(Br[j], Bi[j]);
    dft8(Ar, Ai); twiddle7(Ar, Ai, c2, s2);
    #pragma unroll
    for (int a = 0; a < 8; ++a) {
        float2 v = LC[k1*68+8*a+b]; Br[a] = v.x; Bi[a] = v.y;
    }
    dft8(Br, Bi); twiddle7(Br, Bi, c2, s2);
    #pragma unroll
    for (int cc = 0; cc < 8; ++cc) {
        int ad = k1*68 + 8*cc + ((b + cc) & 7);
        LC[ad] = make_float2(Ar[cc], Ai[cc]);
    }
    #pragma unroll
    for (int bb = 0; bb < 8; ++bb) {
        int ad = k1*68 + 8*b + ((bb + b) & 7);
        float2 v = LC[ad]; Ar[bb] = v.x; Ai[bb] = v.y;
    }
    #pragma unroll
    for (int cc = 0; cc < 8; ++cc) {
        int ad = k1*68 + 8*cc + ((b + cc) & 7);
        LC[ad] = make_float2(Br[cc], Bi[cc]);
    }
    dft8(Ar, Ai);
    #pragma unroll
    for (int bb = 0; bb < 8; ++bb) {
        int ad = k1*68 + 8*b + ((bb + b) & 7);
        float2 v = LC[ad]; Br[bb] = v.x; Bi[bb] = v.y;
    }
    dft8(Br, Bi);
}

// Row stage (R13-exact, proven).
__global__ __launch_bounds__(256, 4) void k_rowfft(const float* __restrict__ pred,
                                                   const float* __restrict__ tgt,
                                                   float* __restrict__ ws) {
    __shared__ float smem[4352];
    int t = threadIdx.x, lane = t & 63, w = t >> 6;
    int b = blockIdx.x;
    int img = b >> 6;
    int r0 = (b & 63) << 3;
    int rA = r0 + 2*w;
    const float* pA = pred + (size_t)img*PLANE + (size_t)rA*HW;
    const float* tA = tgt  + (size_t)img*PLANE + (size_t)rA*HW;
    float arA[8], aiA[8], arB[8], aiB[8];
    #pragma unroll
    for (int j = 0; j < 8; ++j) {
        arA[j] = pA[64*j + lane];      aiA[j] = tA[64*j + lane];
        arB[j] = pA[HW + 64*j + lane]; aiB[j] = tA[HW + 64*j + lane];
    }
    float* Lr = smem + w*1088;
    float* Li = Lr + 544;
    fft512x2(arA, aiA, arB, aiB, Lr, Li, lane);
    float PrA[4], PiA[4], TrA[4], TiA[4], P256A=0.f, T256A=0.f;
    float PrB[4], PiB[4], TrB[4], TiB[4], P256B=0.f, T256B=0.f;
    #pragma unroll
    for (int d = 0; d < 8; ++d) {
        int k = (lane>>3) + ((lane&7)<<3) + (d<<6);
        Lr[k] = arA[d]; Li[k] = aiA[d];
    }
    #pragma unroll
    for (int m = 0; m < 4; ++m) {
        int kk = 64*m + lane, j2 = (512 - kk) & 511;
        float z1r = Lr[kk], z1i = Li[kk], z2r = Lr[j2], z2i = Li[j2];
        PrA[m] = 0.5f*(z1r+z2r); PiA[m] = 0.5f*(z1i-z2i);
        TrA[m] = 0.5f*(z1i+z2i); TiA[m] = 0.5f*(z2r-z1r);
    }
    if (lane == 0) { P256A = Lr[256]; T256A = Li[256]; }
    #pragma unroll
    for (int d = 0; d < 8; ++d) {
        int k = (lane>>3) + ((lane&7)<<3) + (d<<6);
        Lr[k] = arB[d]; Li[k] = aiB[d];
    }
    #pragma unroll
    for (int m = 0; m < 4; ++m) {
        int kk = 64*m + lane, j2 = (512 - kk) & 511;
        float z1r = Lr[kk], z1i = Li[kk], z2r = Lr[j2], z2i = Li[j2];
        PrB[m] = 0.5f*(z1r+z2r); PiB[m] = 0.5f*(z1i-z2i);
        TrB[m] = 0.5f*(z1i+z2i); TiB[m] = 0.5f*(z2r-z1r);
    }
    if (lane == 0) { P256B = Lr[256]; T256B = Li[256]; }

    float* tR = smem;                      // [8][260]
    float* tI = smem + 2080;
    __syncthreads();
    #pragma unroll
    for (int m = 0; m < 4; ++m) {
        int kk = 64*m + lane;
        tR[(2*w)*260 + kk]   = PrA[m]; tR[(2*w+1)*260 + kk] = PrB[m];
        tI[(2*w)*260 + kk]   = PiA[m]; tI[(2*w+1)*260 + kk] = PiB[m];
    }
    if (lane == 0) {
        tR[(2*w)*260 + 256] = P256A; tR[(2*w+1)*260 + 256] = P256B;
        tI[(2*w)*260 + 256] = 0.f;   tI[(2*w+1)*260 + 256] = 0.f;
    }
    __syncthreads();
    for (int idx = t; idx < 1040; idx += 256) {
        int comp = idx >= 520;
        int q = idx - (comp ? 520 : 0);
        int cg = q >> 3, rl = q & 7;
        const float* Tt = comp ? tI : tR;
        float4 v = *(const float4*)(Tt + rl*260 + 4*cg);
        float* outP = ws + (size_t)(comp ? OFF_PIm : OFF_PR)
                      + (size_t)img*CP2 + cg*2048 + (r0 + rl)*4;
        *(float4*)outP = v;
    }
    __syncthreads();
    #pragma unroll
    for (int m = 0; m < 4; ++m) {
        int kk = 64*m + lane;
        tR[(2*w)*260 + kk]   = TrA[m]; tR[(2*w+1)*260 + kk] = TrB[m];
        tI[(2*w)*260 + kk]   = TiA[m]; tI[(2*w+1)*260 + kk] = TiB[m];
    }
    if (lane == 0) {
        tR[(2*w)*260 + 256] = T256A; tR[(2*w+1)*260 + 256] = T256B;
        tI[(2*w)*260 + 256] = 0.f;   tI[(2*w+1)*260 + 256] = 0.f;
    }
    __syncthreads();
    for (int idx = t; idx < 1040; idx += 256) {
        int comp = idx >= 520;
        int q = idx - (comp ? 520 : 0);
        int cg = q >> 3, rl = q & 7;
        const float* Tt = comp ? tI : tR;
        float4 v = *(const float4*)(Tt + rl*260 + 4*cg);
        float* outP = ws + (size_t)(comp ? OFF_TI : OFF_TR)
                      + (size_t)img*CP2 + cg*2048 + (r0 + rl)*4;
        *(float4*)outP = v;
    }
}

// Flush helper: run-collapsed atomic pair.
__device__ __forceinline__ void flush2(float* binM, float* binD, int k,
                                       float aM, float aD) {
    atomicAdd(&binM[k], aM);
    atomicAdd(&binD[k], aD);
}

// Col stage (R15-exact: float2-fused scratch, direct indexing — measured 41.7us).
__global__ __launch_bounds__(256, 4) void k_colfft(const float* __restrict__ ws,
                                                   float* __restrict__ gPM,
                                                   float* __restrict__ gPD) {
    __shared__ __align__(16) float2 smem2[2176];
    __shared__ float binM[NB], binD[NB];
    int t = threadIdx.x, lane = t & 63, w = t >> 6;
    for (int j = t; j < NB; j += 256) { binM[j] = 0.f; binD[j] = 0.f; }
    __syncthreads();
    int b = blockIdx.x;
    int img = b / NG;
    int g = b - img*NG;
    int c = 4*g + w;
    if (c < NC) {
        float2* LC = smem2 + w*544;
        float prm[8], pim[8], trm[8], tim[8];
        size_t cbase = (size_t)img*CP2 + (size_t)(c >> 2)*2048 + (c & 3);
        const float* cPR = ws + OFF_PR  + cbase;
        const float* cPI = ws + OFF_PIm + cbase;
        const float* cTR = ws + OFF_TR  + cbase;
        const float* cTI = ws + OFF_TI  + cbase;
        #pragma unroll
        for (int j = 0; j < 8; ++j) {
            int o = (64*j + lane) << 2;
            prm[j] = cPR[o]; pim[j] = cPI[o];
            trm[j] = cTR[o]; tim[j] = cTI[o];
        }
        fft512x2f2(prm, pim, trm, tim, LC, lane);
        #pragma unroll
        for (int d = 0; d < 8; ++d) {
            int ky = (lane>>3) + ((lane&7)<<3) + (d<<6);
            float sp  = prm[d]*prm[d] + pim[d]*pim[d];
            float st_ = trm[d]*trm[d] + tim[d]*tim[d];
            float diff = sp - st_;
            float er = prm[d] + 1e-8f;
            LC[ky] = make_float2(10.0f * __logf(er*er + pim[d]*pim[d]), diff*diff);
        }
        __builtin_amdgcn_wave_barrier();
        // ---- contiguous-pair binning: lane owns p = 4*lane .. 4*lane+3 ----
        int p0 = 4*lane;
        float4 q0  = *(const float4*)(LC + p0);        // m[p0],d[p0],m[p0+1],d[p0+1]
        float4 q1  = *(const float4*)(LC + p0 + 2);    // p0+2, p0+3
        float4 r0v = *(const float4*)(LC + (508 - p0)); // 508-p0, 509-p0
        float4 r1v = *(const float4*)(LC + (510 - p0)); // 510-p0, 511-p0
        float2 e2 = LC[p0 + 4];                        // p0+4 <= 256
        float2 g2 = LC[(512 - p0) & 511];
        // main pass: s[j] = L[p0+j] + L[511-(p0+j)]
        float sM[4], sD[4];
        sM[0]=q0.x+r1v.z; sM[1]=q0.z+r1v.x; sM[2]=q1.x+r0v.z; sM[3]=q1.z+r0v.x;
        sD[0]=q0.y+r1v.w; sD[1]=q0.w+r1v.y; sD[2]=q1.y+r0v.w; sD[3]=q1.w+r0v.y;
        float v1 = (c == 256) ? 511.0f : (float)(2*c + 1);
        {
            int kp = rbin_odd((float)(2*p0 + 1), v1);
            float aM = sM[0], aD = sD[0];
            #pragma unroll
            for (int j = 1; j < 4; ++j) {
                int k = rbin_odd((float)(2*(p0 + j) + 1), v1);
                if (k == kp) { aM += sM[j]; aD += sD[j]; }
                else { flush2(binM, binD, kp, aM, aD); kp = k; aM = sM[j]; aD = sD[j]; }
            }
            flush2(binM, binD, kp, aM, aD);
        }
        if (c >= 1 && c <= 255) {
            // mirror pass: s2[j] = L[(512-(p0+j))&511] + L[p0+j+1]
            float s2M[4], s2D[4];
            s2M[0]=g2.x+q0.z;   s2D[0]=g2.y+q0.w;
            s2M[1]=r1v.z+q1.x;  s2D[1]=r1v.w+q1.y;
            s2M[2]=r1v.x+q1.z;  s2D[2]=r1v.y+q1.w;
            s2M[3]=r0v.z+e2.x;  s2D[3]=r0v.w+e2.y;
            float v2 = (float)(2*c - 1);
            int kp = rbin_odd((float)(2*p0 + 1), v2);
            float aM = s2M[0], aD = s2D[0];
            #pragma unroll
            for (int j = 1; j < 4; ++j) {
                int k = rbin_odd((float)(2*(p0 + j) + 1), v2);
                if (k == kp) { aM += s2M[j]; aD += s2D[j]; }
                else { flush2(binM, binD, kp, aM, aD); kp = k; aM = s2M[j]; aD = s2D[j]; }
            }
            flush2(binM, binD, kp, aM, aD);
        }
    }
    __syncthreads();
    for (int j = t; j < NB; j += 256) {
        gPM[(size_t)b*NB + j] = binM[j];
        gPD[(size_t)b*NB + j] = binD[j];
    }
}

// Partial-bin reduction (R13-proven, NG=65).
__global__ __launch_bounds__(256) void k_reduce(const float* __restrict__ gPM,
                                                const float* __restrict__ gPD,
                                                float* __restrict__ rM,
                                                float* __restrict__ rD) {
    __shared__ float sm[8][33], sd2[8][33];
    int b = blockIdx.x;
    int img = b / 12, ch = b - img*12;
    int jl = threadIdx.x & 31, gs = threadIdx.x >> 5;
    int j = ch*32 + jl;
    float aM = 0.f, aD = 0.f;
    if (j < NB) {
        for (int g = gs; g < NG; g += 8) {
            aM += gPM[(size_t)(img*NG + g)*NB + j];
            aD += gPD[(size_t)(img*NG + g)*NB + j];
        }
    }
    sm[gs][jl] = aM; sd2[gs][jl] = aD;
    __syncthreads();
    if (threadIdx.x < 32 && j < NB) {
        float tM = 0.f, tD = 0.f;
        #pragma unroll
        for (int s = 0; s < 8; ++s) { tM += sm[s][jl]; tD += sd2[s][jl]; }
        rM[img*NB + j] = tM;
        rD[img*NB + j] = tD;
    }
}

// Per-image final (R13-proven, unchanged).
__global__ __launch_bounds__(512) void k_final(const float* __restrict__ rM,
                                               const float* __restrict__ rD,
                                               float* __restrict__ out) {
    __shared__ int cnt[NB];
    __shared__ float meanb[NB];
    __shared__ float dsum[NB];
    __shared__ float rmin[512], rmax[512];
    __shared__ double sred[512];
    int t = threadIdx.x, img = blockIdx.x;
    for (int j = t; j < NB; j += 512) cnt[j] = 0;
    __syncthreads();
    {   // thread handles 128 contiguous v for fixed u: q = t*128 + i
        float u = (float)(2*(t >> 1) + 1);
        int vb = (t & 1) << 7;
        int kp = rbin_odd(u, (float)(2*vb + 1));
        int acc = 4;
        for (int i = 1; i < 128; ++i) {
            int k = rbin_odd(u, (float)(2*(vb + i) + 1));
            if (k == kp) acc += 4;
            else { atomicAdd(&cnt[kp], acc); kp = k; acc = 4; }
        }
        atomicAdd(&cnt[kp], acc);
    }
    __syncthreads();
    for (int j = t; j < NB; j += 512) {
        meanb[j] = rM[img*NB + j] / (float)cnt[j];
        dsum[j]  = rD[img*NB + j];
    }
    __syncthreads();
    float vmin = INFINITY, vmax = -INFINITY;
    if (t >= 1 && t <= 360) { vmin = meanb[t]; vmax = meanb[t]; }
    rmin[t] = vmin; rmax[t] = vmax;
    __syncthreads();
    for (int s = 256; s > 0; s >>= 1) {
        if (t < s) {
            float a = rmin[t], bb = rmin[t+s];
            rmin[t] = (a != a || bb != bb) ? __int_as_float(0x7fc00000) : fminf(a, bb);
            a = rmax[t]; bb = rmax[t+s];
            rmax[t] = (a != a || bb != bb) ? __int_as_float(0x7fc00000) : fmaxf(a, bb);
        }
        __syncthreads();
    }
    float pmin = rmin[0], pmax = rmax[0];
    double part = 0.0;
    for (int k = t; k < NB; k += 512) {
        float wgt;
        if (k == NB - 1) {
            wgt = 1.0f;
        } else {
            int idx = (k == 0) ? 1 : k;
            float e = (meanb[idx] - pmin) / (pmax - pmin);
            float wv = 1.0f - e;
            if (wv != wv) wv = 0.0f;
            wv = fminf(fmaxf(wv, 0.0f), 1.0f);
            wgt = wv;
        }
        part += (double)wgt * (double)dsum[k];
    }
    sred[t] = part;
    __syncthreads();
    for (int s = 256; s > 0; s >>= 1) {
        if (t < s) sred[t] += sred[t+s];
        __syncthreads();
    }
    if (t == 0) atomicAdd(out, (float)(sred[0] / 6291456.0));
}

extern "C" void kernel_launch(void* const* d_in, const int* in_sizes, int n_in,
                              void* d_out, int out_size, void* d_ws, size_t ws_size,
                              hipStream_t stream) {
    const float* pred = (const float*)d_in[0];
    const float* tgt  = (const float*)d_in[1];
    float* ws = (float*)d_ws;
    hipMemsetAsync(d_out, 0, sizeof(float), stream);
    k_rowfft<<<NIMG*64, 256, 0, stream>>>(pred, tgt, ws);
    k_colfft<<<NPB, 256, 0, stream>>>(ws, ws + OFF_PM, ws + OFF_PD);
    k_reduce<<<NIMG*12, 256, 0, stream>>>(ws + OFF_PM, ws + OFF_PD,
                                          ws + OFF_RM, ws + OFF_RD);
    k_final<<<NIMG, 512, 0, stream>>>(ws + OFF_RM, ws + OFF_RD, (float*)d_out);
}